// Round 7
// baseline (253.925 us; speedup 1.0000x reference)
//
#include <hip/hip_runtime.h>
#include <hip/hip_bf16.h>
#include <math.h>

#define LN2F 0.6931471805599453f

// ---------------------------------------------------------------------------
// Circulant trick: y[b, j*1024+i] = sum_k x[b,k] W[(i+k)%1024, j] is circular
// cross-correlation -> y_row = IDFT( Wf_j * conj(X_b) ), length-1024.
// Output only feeds sum_i logcosh(.) so ORDER IS IRRELEVANT: use radix-4 DIF
// forward (natural -> digit-reversed) and its adjoint radix-4 DIT inverse
// (digit-reversed -> natural) -- no bit-reversal anywhere, elementwise product
// is valid in the permuted domain. Two real outputs pack per complex IFFT:
// IFFT(G_j + i*G_{j+1}) = y_j + i*y_{j+1}.
// Per-wave private 8KB LDS array -> NO barriers in the FFT. XOR swizzle
// sigma ^ ((sigma>>4)&15) makes all stage access patterns bank-optimal.
// ---------------------------------------------------------------------------

#define LSW(s) ((s) ^ (((s) >> 4) & 15))

__device__ __forceinline__ float2 cadd(float2 a, float2 b){ return make_float2(a.x+b.x, a.y+b.y); }
__device__ __forceinline__ float2 csub(float2 a, float2 b){ return make_float2(a.x-b.x, a.y-b.y); }
__device__ __forceinline__ float2 cmul(float2 a, float2 b){ return make_float2(a.x*b.x - a.y*b.y, a.x*b.y + a.y*b.x); }
__device__ __forceinline__ float2 cmulj(float2 a, float2 b){ return make_float2(a.x*b.x + a.y*b.y, a.y*b.x - a.x*b.y); } // a*conj(b)

// TWF[m] = e^{-2*pi*i*m/1024} for the compile-time m we need
__device__ __forceinline__ float2 Ctw(int m) {
  switch (m) {
    case 0:   return make_float2(1.f, 0.f);
    case 1:   return make_float2(0.999981175f, -0.006135885f);
    case 2:   return make_float2(0.999924702f, -0.012271538f);
    case 3:   return make_float2(0.999830582f, -0.018406730f);
    case 64:  return make_float2(0.923879533f, -0.382683432f);
    case 128: return make_float2(0.707106781f, -0.707106781f);
    case 192: return make_float2(0.382683432f, -0.923879533f);
    case 256: return make_float2(0.f, -1.f);
    case 384: return make_float2(-0.707106781f, -0.707106781f);
    case 576: return make_float2(-0.923879533f, 0.382683432f);
  }
  return make_float2(1.f, 0.f);
}

// forward DIF butterfly (output twiddles, e^{-})
#define BFLY_F(x0,x1,x2,x3,W1,W2,W3,y0,y1,y2,y3) do { \
  float2 t0 = cadd(x0,x2), t1 = cadd(x1,x3), t2 = csub(x0,x2), d_ = csub(x1,x3); \
  float2 t3 = make_float2(d_.y, -d_.x); \
  y0 = cadd(t0,t1); y1 = cmul(cadd(t2,t3), W1); \
  y2 = cmul(csub(t0,t1), W2); y3 = cmul(csub(t2,t3), W3); } while(0)

// inverse DIT butterfly (input conj-twiddles, e^{+})
#define BFLY_I(x0,x1,x2,x3,W1,W2,W3,y0,y1,y2,y3) do { \
  float2 u1 = cmulj(x1,W1), u2 = cmulj(x2,W2), u3 = cmulj(x3,W3); \
  float2 t0 = cadd(x0,u2), t1 = cadd(u1,u3), t2 = csub(x0,u2), d_ = csub(u1,u3); \
  float2 t3 = make_float2(-d_.y, d_.x); \
  y0 = cadd(t0,t1); y1 = cadd(t2,t3); y2 = csub(t0,t1); y3 = csub(t2,t3); } while(0)

#define BFLY_I1(x0,x1,x2,x3,y0,y1,y2,y3) do { \
  float2 t0 = cadd(x0,x2), t1 = cadd(x1,x3), t2 = csub(x0,x2), d_ = csub(x1,x3); \
  float2 t3 = make_float2(-d_.y, d_.x); \
  y0 = cadd(t0,t1); y1 = cadd(t2,t3); y2 = csub(t0,t1); y3 = csub(t2,t3); } while(0)

__device__ __forceinline__ float lc(float v) {  // logcosh + ln2
  float a = fabsf(v);
  return a + __logf(1.f + __expf(-2.f * a));
}

__global__ void k_twiddle(float2* __restrict__ tw) {
  int m = blockIdx.x * 256 + threadIdx.x;
  float th = (float)(2.0 * M_PI / 1024.0) * (float)m;
  tw[m] = make_float2(cosf(th), -sinf(th));
}

// Forward FFT-1024 (radix-4 DIF, natural in -> digit-reversed content at
// natural slots). One wave per row, 4 rows/block. Real input.
__global__ __launch_bounds__(256, 3) void k_fft_fwd(
    const float* __restrict__ src, int estride, int rstride,
    const float2* __restrict__ tw, float2* __restrict__ dst,
    const float* __restrict__ vbias, float* __restrict__ out, int dorow) {
  __shared__ __align__(16) float2 fft[4][1024];
  int tid = threadIdx.x, wv = tid >> 6, u = tid & 63;
  int row = blockIdx.x * 4 + wv;
  const float* xr = src + (size_t)row * rstride;
  float2* L = fft[wv];
  float2 twu = tw[u];
  float2 tw4u = tw[4 * u];
  int tp = u & 3;
  float2 tw16t = tw[16 * tp], tw64t = tw[64 * tp];

  float vr[4][4]; float rs = 0.f;
  #pragma unroll
  for (int a = 0; a < 4; ++a)
    #pragma unroll
    for (int k = 0; k < 4; ++k) {
      float s = xr[(u + 64 * a + 256 * k) * estride];
      vr[a][k] = s; rs += s;
    }
  // s4 (L=1024, q=256): butterfly over k, m = u + 64a. Real-input simplified.
  float2 v[4][4];
  #pragma unroll
  for (int a = 0; a < 4; ++a) {
    float x0 = vr[a][0], x1 = vr[a][1], x2 = vr[a][2], x3 = vr[a][3];
    float t0 = x0 + x2, t1 = x1 + x3, t2 = x0 - x2, dm = x1 - x3;
    float2 W1 = cmul(twu, Ctw(64 * a));
    float2 W2 = cmul(W1, W1), W3 = cmul(W1, W2);
    v[a][0] = make_float2(t0 + t1, 0.f);
    v[a][1] = cmul(make_float2(t2, -dm), W1);
    v[a][2] = cmul(make_float2(t0 - t1, 0.f), W2);
    v[a][3] = cmul(make_float2(t2, dm), W3);
  }
  // s3 (L=256, q=64): butterfly over a, m = 4u (same for all k)
  {
    float2 W1 = tw4u, W2 = cmul(W1, W1), W3 = cmul(W1, W2);
    #pragma unroll
    for (int k = 0; k < 4; ++k) {
      float2 y0,y1,y2,y3;
      BFLY_F(v[0][k], v[1][k], v[2][k], v[3][k], W1, W2, W3, y0,y1,y2,y3);
      v[0][k]=y0; v[1][k]=y1; v[2][k]=y2; v[3][k]=y3;
    }
  }
  #pragma unroll
  for (int a = 0; a < 4; ++a)
    #pragma unroll
    for (int k = 0; k < 4; ++k)
      L[LSW(u + 64 * a + 256 * k)] = v[a][k];

  // s2 (L=64, q=16, m = 64a'+16t'') + s1 (L=16, q=4, m = 64t'') fused
  int D = u >> 2;
  float2 w[4][4];
  #pragma unroll
  for (int c = 0; c < 4; ++c)
    #pragma unroll
    for (int ap = 0; ap < 4; ++ap)
      w[c][ap] = L[LSW(64 * D + 16 * c + 4 * ap + tp)];
  #pragma unroll
  for (int ap = 0; ap < 4; ++ap) {
    float2 W1 = cmul(Ctw(64 * ap), tw16t);
    float2 W2 = cmul(W1, W1), W3 = cmul(W1, W2);
    float2 y0,y1,y2,y3;
    BFLY_F(w[0][ap], w[1][ap], w[2][ap], w[3][ap], W1, W2, W3, y0,y1,y2,y3);
    w[0][ap]=y0; w[1][ap]=y1; w[2][ap]=y2; w[3][ap]=y3;
  }
  {
    float2 W1 = tw64t, W2 = cmul(W1, W1), W3 = cmul(W1, W2);
    #pragma unroll
    for (int c = 0; c < 4; ++c) {
      float2 y0,y1,y2,y3;
      BFLY_F(w[c][0], w[c][1], w[c][2], w[c][3], W1, W2, W3, y0,y1,y2,y3);
      w[c][0]=y0; w[c][1]=y1; w[c][2]=y2; w[c][3]=y3;
    }
  }
  #pragma unroll
  for (int c = 0; c < 4; ++c)
    #pragma unroll
    for (int ap = 0; ap < 4; ++ap)
      L[LSW(64 * D + 16 * c + 4 * ap + tp)] = w[c][ap];

  // s0 (L=4, W=1): 16 consecutive slots per thread, store to global
  float2* drow = dst + (size_t)row * 1024;
  #pragma unroll
  for (int j = 0; j < 4; ++j) {
    float2 z0 = L[LSW(16 * u + 4 * j)];
    float2 z1 = L[LSW(16 * u + 4 * j + 1)];
    float2 z2 = L[LSW(16 * u + 4 * j + 2)];
    float2 z3 = L[LSW(16 * u + 4 * j + 3)];
    float2 t0 = cadd(z0,z2), t1 = cadd(z1,z3), t2 = csub(z0,z2), d = csub(z1,z3);
    float2 t3 = make_float2(d.y, -d.x);
    float2 y0 = cadd(t0,t1), y1 = cadd(t2,t3), y2 = csub(t0,t1), y3 = csub(t2,t3);
    float4* dp = (float4*)(drow + 16 * u + 4 * j);
    dp[0] = make_float4(y0.x, y0.y, y1.x, y1.y);
    dp[1] = make_float4(y2.x, y2.y, y3.x, y3.y);
  }
  if (dorow) {
    #pragma unroll
    for (int m = 32; m; m >>= 1) rs += __shfl_down(rs, m);
    if (u == 0) out[row] = vbias[0] * rs;
  }
}

// Per b: 8 packed IFFTs (2 j's each) + logcosh + reduce. Wave-private LDS,
// no barriers in the main loop.
__global__ __launch_bounds__(256, 3) void k_corr(
    const float2* __restrict__ X, const float2* __restrict__ Wfs,
    const float* __restrict__ bs, const float2* __restrict__ tw,
    float* __restrict__ out) {
  __shared__ __align__(16) float2 fft[4][1024];
  __shared__ float red[4];
  int tid = threadIdx.x, wv = tid >> 6, u = tid & 63;
  int b = blockIdx.x;
  float2* L = fft[wv];
  float2 tw4u = tw[4 * u];
  int t = u & 15, B = u >> 4;
  float2 tw16t = tw[16 * t], tw4t = tw[4 * t];

  float2 Xr[16];
  const float4* Xp = (const float4*)(X + (size_t)b * 1024 + 16 * u);
  #pragma unroll
  for (int m = 0; m < 8; ++m) {
    float4 q4 = Xp[m];
    Xr[2*m]   = make_float2(q4.x, q4.y);
    Xr[2*m+1] = make_float2(q4.z, q4.w);
  }
  float acc = 0.f;
  for (int qq = 0; qq < 2; ++qq) {
    int p = wv * 2 + qq;
    const float4* W0p = (const float4*)(Wfs + (size_t)(2*p) * 1024 + 16 * u);
    const float4* W1p = (const float4*)(Wfs + (size_t)(2*p+1) * 1024 + 16 * u);
    float bs0 = bs[2*p], bs1 = bs[2*p+1];
    // H = (Wf_j * conj(X) + i * Wf_{j+1} * conj(X)) / 1024 at slots 16u..16u+15
    float2 z[16];
    #pragma unroll
    for (int m = 0; m < 8; ++m) {
      float4 qa = W0p[m], qb = W1p[m];
      float2 g1 = cmulj(make_float2(qa.x, qa.y), Xr[2*m]);
      float2 g2 = cmulj(make_float2(qb.x, qb.y), Xr[2*m]);
      z[2*m] = make_float2((g1.x - g2.y) * 9.765625e-4f, (g1.y + g2.x) * 9.765625e-4f);
      g1 = cmulj(make_float2(qa.z, qa.w), Xr[2*m+1]);
      g2 = cmulj(make_float2(qb.z, qb.w), Xr[2*m+1]);
      z[2*m+1] = make_float2((g1.x - g2.y) * 9.765625e-4f, (g1.y + g2.x) * 9.765625e-4f);
    }
    // s0 (W=1): over i within each 4
    #pragma unroll
    for (int j = 0; j < 4; ++j) {
      float2 y0,y1,y2,y3;
      BFLY_I1(z[4*j], z[4*j+1], z[4*j+2], z[4*j+3], y0,y1,y2,y3);
      z[4*j]=y0; z[4*j+1]=y1; z[4*j+2]=y2; z[4*j+3]=y3;
    }
    // s1: over j per i, m = 64i (compile-time twiddles)
    #pragma unroll
    for (int i = 0; i < 4; ++i) {
      float2 y0,y1,y2,y3;
      BFLY_I(z[i], z[4+i], z[8+i], z[12+i], Ctw(64*i), Ctw(128*i), Ctw(192*i), y0,y1,y2,y3);
      z[i]=y0; z[4+i]=y1; z[8+i]=y2; z[12+i]=y3;
    }
    #pragma unroll
    for (int r = 0; r < 16; ++r) L[LSW(16*u + r)] = z[r];
    // s2 (m=16t) + s3 (m=4t+64a) fused; unit slots 256B + 64c + 16a + t
    float2 w[4][4];
    #pragma unroll
    for (int a = 0; a < 4; ++a)
      #pragma unroll
      for (int c = 0; c < 4; ++c)
        w[a][c] = L[LSW(256*B + 64*c + 16*a + t)];
    {
      float2 W1 = tw16t, W2 = cmul(W1,W1), W3 = cmul(W1,W2);
      #pragma unroll
      for (int c = 0; c < 4; ++c) {
        float2 y0,y1,y2,y3;
        BFLY_I(w[0][c], w[1][c], w[2][c], w[3][c], W1, W2, W3, y0,y1,y2,y3);
        w[0][c]=y0; w[1][c]=y1; w[2][c]=y2; w[3][c]=y3;
      }
    }
    #pragma unroll
    for (int a = 0; a < 4; ++a) {
      float2 W1 = cmul(tw4t, Ctw(64*a));
      float2 W2 = cmul(W1,W1), W3 = cmul(W1,W2);
      float2 y0,y1,y2,y3;
      BFLY_I(w[a][0], w[a][1], w[a][2], w[a][3], W1, W2, W3, y0,y1,y2,y3);
      w[a][0]=y0; w[a][1]=y1; w[a][2]=y2; w[a][3]=y3;
    }
    #pragma unroll
    for (int a = 0; a < 4; ++a)
      #pragma unroll
      for (int c = 0; c < 4; ++c)
        L[LSW(256*B + 64*c + 16*a + t)] = w[a][c];
    // s4 (m = 4u+i) + logcosh: re -> j0, im -> j1
    #pragma unroll
    for (int i = 0; i < 4; ++i) {
      float2 x0 = L[LSW(4*u + i)];
      float2 x1 = L[LSW(4*u + i + 256)];
      float2 x2 = L[LSW(4*u + i + 512)];
      float2 x3 = L[LSW(4*u + i + 768)];
      float2 W1 = cmul(tw4u, Ctw(i));
      float2 W2 = cmul(W1,W1), W3 = cmul(W1,W2);
      float2 y0,y1,y2,y3;
      BFLY_I(x0,x1,x2,x3,W1,W2,W3,y0,y1,y2,y3);
      acc += lc(y0.x + bs0) + lc(y0.y + bs1);
      acc += lc(y1.x + bs0) + lc(y1.y + bs1);
      acc += lc(y2.x + bs0) + lc(y2.y + bs1);
      acc += lc(y3.x + bs0) + lc(y3.y + bs1);
    }
  }
  #pragma unroll
  for (int m = 32; m; m >>= 1) acc += __shfl_down(acc, m);
  if (u == 0) red[wv] = acc;
  __syncthreads();
  if (tid == 0)
    out[b] += red[0] + red[1] + red[2] + red[3] - 16384.f * LN2F;
}

// fallback if workspace is too small: correct but slow
__global__ void k_naive(const float* __restrict__ x, const float* __restrict__ W,
                        const float* __restrict__ bs, const float* __restrict__ vb,
                        float* __restrict__ out) {
  int b = blockIdx.x;
  __shared__ float xs[1024];
  __shared__ float red[256];
  int t = threadIdx.x;
  float xsum = 0.f;
  for (int i = t; i < 1024; i += 256) { float v = x[(size_t)b * 1024 + i]; xs[i] = v; xsum += v; }
  __syncthreads();
  float tot = vb[0] * xsum;
  for (int h = t; h < 16384; h += 256) {
    int j = h >> 10, kh = h & 1023;
    float a = bs[j];
    for (int i = 0; i < 1024; ++i) a += xs[i] * W[((i + kh) & 1023) * 16 + j];
    float ax = fabsf(a);
    tot += ax + __logf(1.f + __expf(-2.f * ax)) - LN2F;
  }
  red[t] = tot;
  __syncthreads();
  for (int s2 = 128; s2; s2 >>= 1) { if (t < s2) red[t] += red[t + s2]; __syncthreads(); }
  if (t == 0) out[b] = red[0];
}

extern "C" void kernel_launch(void* const* d_in, const int* in_sizes, int n_in,
                              void* d_out, int out_size, void* d_ws, size_t ws_size,
                              hipStream_t stream) {
  const float* x  = (const float*)d_in[0];   // [4096,1024]
  const float* W  = (const float*)d_in[1];   // [1024,16]
  const float* bs = (const float*)d_in[2];   // [16]
  const float* vb = (const float*)d_in[3];   // [1]
  float* out = (float*)d_out;                // [4096]

  size_t need = 8192 + 131072 + (size_t)4096 * 1024 * 8;  // tw + Wfs + X
  if (ws_size < need) {
    k_naive<<<4096, 256, 0, stream>>>(x, W, bs, vb, out);
    return;
  }
  float2* tw  = (float2*)d_ws;
  float2* Wfs = (float2*)((char*)d_ws + 8192);
  float2* X   = (float2*)((char*)d_ws + 8192 + 131072);

  k_twiddle<<<4, 256, 0, stream>>>(tw);
  // 16 W-column spectra: w_j[m] = W[m*16 + j]
  k_fft_fwd<<<4, 256, 0, stream>>>(W, 16, 1, tw, Wfs, vb, out, 0);
  // 4096 x-row spectra; also out[row] = vb * rowsum(x[row])
  k_fft_fwd<<<1024, 256, 0, stream>>>(x, 1, 1024, tw, X, vb, out, 1);
  k_corr<<<4096, 256, 0, stream>>>(X, Wfs, bs, tw, out);
}

// Round 8
// 156.428 us; speedup vs baseline: 1.6233x; 1.6233x over previous
//
#include <hip/hip_runtime.h>
#include <hip/hip_bf16.h>
#include <math.h>

#define LN2F 0.6931471805599453f
#define SCL 9.765625e-4f   // 1/1024

// ---------------------------------------------------------------------------
// Circulant trick: y[b, j*1024+i] = sum_k x[b,k] W[(i+k)%1024, j] is circular
// cross-correlation -> y_row = IDFT( Wf_j * conj(X_b) ), length-1024.
// Output only feeds sum_i logcosh(.) so order is irrelevant: radix-4 DIF
// forward (natural -> digit-reversed) and adjoint radix-4 DIT inverse
// (digit-reversed -> natural) -- no bit reversal; pointwise product valid in
// the permuted domain. Two real outputs per complex IFFT:
// IFFT(G_j + i*G_{j+1}) = y_j + i*y_{j+1}.
// k_corr is written with ZERO per-thread arrays (named scalars only) so
// nothing can be demoted to scratch (round-7 showed 367MB of spill traffic).
// ---------------------------------------------------------------------------

#define LSW(s) ((s) ^ (((s) >> 4) & 15))

__device__ __forceinline__ float2 cadd(float2 a, float2 b){ return make_float2(a.x+b.x, a.y+b.y); }
__device__ __forceinline__ float2 csub(float2 a, float2 b){ return make_float2(a.x-b.x, a.y-b.y); }
__device__ __forceinline__ float2 cmul(float2 a, float2 b){ return make_float2(a.x*b.x - a.y*b.y, a.x*b.y + a.y*b.x); }
__device__ __forceinline__ float2 cmulj(float2 a, float2 b){ return make_float2(a.x*b.x + a.y*b.y, a.y*b.x - a.x*b.y); } // a*conj(b)

// TWF[m] = e^{-2*pi*i*m/1024} for the compile-time m we need
__device__ __forceinline__ float2 Ctw(int m) {
  switch (m) {
    case 0:   return make_float2(1.f, 0.f);
    case 1:   return make_float2(0.999981175f, -0.006135885f);
    case 2:   return make_float2(0.999924702f, -0.012271538f);
    case 3:   return make_float2(0.999830582f, -0.018406730f);
    case 64:  return make_float2(0.923879533f, -0.382683432f);
    case 128: return make_float2(0.707106781f, -0.707106781f);
    case 192: return make_float2(0.382683432f, -0.923879533f);
    case 256: return make_float2(0.f, -1.f);
    case 384: return make_float2(-0.707106781f, -0.707106781f);
    case 576: return make_float2(-0.923879533f, 0.382683432f);
  }
  return make_float2(1.f, 0.f);
}

// forward DIF butterfly (output twiddles, e^{-})
#define BFLY_F(x0,x1,x2,x3,W1,W2,W3,y0,y1,y2,y3) do { \
  float2 t0 = cadd(x0,x2), t1 = cadd(x1,x3), t2 = csub(x0,x2), d_ = csub(x1,x3); \
  float2 t3 = make_float2(d_.y, -d_.x); \
  y0 = cadd(t0,t1); y1 = cmul(cadd(t2,t3), W1); \
  y2 = cmul(csub(t0,t1), W2); y3 = cmul(csub(t2,t3), W3); } while(0)

// inverse DIT butterfly (input conj-twiddles, e^{+})
#define BFLY_I(x0,x1,x2,x3,W1,W2,W3,y0,y1,y2,y3) do { \
  float2 u1 = cmulj(x1,W1), u2 = cmulj(x2,W2), u3 = cmulj(x3,W3); \
  float2 t0 = cadd(x0,u2), t1 = cadd(u1,u3), t2 = csub(x0,u2), d_ = csub(u1,u3); \
  float2 t3 = make_float2(-d_.y, d_.x); \
  y0 = cadd(t0,t1); y1 = cadd(t2,t3); y2 = csub(t0,t1); y3 = csub(t2,t3); } while(0)

#define BFLY_I1(x0,x1,x2,x3,y0,y1,y2,y3) do { \
  float2 t0 = cadd(x0,x2), t1 = cadd(x1,x3), t2 = csub(x0,x2), d_ = csub(x1,x3); \
  float2 t3 = make_float2(-d_.y, d_.x); \
  y0 = cadd(t0,t1); y1 = cadd(t2,t3); y2 = csub(t0,t1); y3 = csub(t2,t3); } while(0)

__device__ __forceinline__ float lc(float v) {  // logcosh + ln2
  float a = fabsf(v);
  return a + __logf(1.f + __expf(-2.f * a));
}

__global__ void k_twiddle(float2* __restrict__ tw) {
  int m = blockIdx.x * 256 + threadIdx.x;
  float th = (float)(2.0 * M_PI / 1024.0) * (float)m;
  tw[m] = make_float2(cosf(th), -sinf(th));
}

// Forward FFT-1024 (radix-4 DIF). One wave per row, 4 rows/block. Real input.
__global__ __launch_bounds__(256, 3) void k_fft_fwd(
    const float* __restrict__ src, int estride, int rstride,
    const float2* __restrict__ tw, float2* __restrict__ dst,
    const float* __restrict__ vbias, float* __restrict__ out, int dorow) {
  __shared__ __align__(16) float2 fft[4][1024];
  int tid = threadIdx.x, wv = tid >> 6, u = tid & 63;
  int row = blockIdx.x * 4 + wv;
  const float* xr = src + (size_t)row * rstride;
  float2* L = fft[wv];
  float2 twu = tw[u];
  float2 tw4u = tw[4 * u];
  int tp = u & 3;
  float2 tw16t = tw[16 * tp], tw64t = tw[64 * tp];

  float vr[4][4]; float rs = 0.f;
  #pragma unroll
  for (int a = 0; a < 4; ++a)
    #pragma unroll
    for (int k = 0; k < 4; ++k) {
      float s = xr[(u + 64 * a + 256 * k) * estride];
      vr[a][k] = s; rs += s;
    }
  float2 v[4][4];
  #pragma unroll
  for (int a = 0; a < 4; ++a) {
    float x0 = vr[a][0], x1 = vr[a][1], x2 = vr[a][2], x3 = vr[a][3];
    float t0 = x0 + x2, t1 = x1 + x3, t2 = x0 - x2, dm = x1 - x3;
    float2 W1 = cmul(twu, Ctw(64 * a));
    float2 W2 = cmul(W1, W1), W3 = cmul(W1, W2);
    v[a][0] = make_float2(t0 + t1, 0.f);
    v[a][1] = cmul(make_float2(t2, -dm), W1);
    v[a][2] = cmul(make_float2(t0 - t1, 0.f), W2);
    v[a][3] = cmul(make_float2(t2, dm), W3);
  }
  {
    float2 W1 = tw4u, W2 = cmul(W1, W1), W3 = cmul(W1, W2);
    #pragma unroll
    for (int k = 0; k < 4; ++k) {
      float2 y0,y1,y2,y3;
      BFLY_F(v[0][k], v[1][k], v[2][k], v[3][k], W1, W2, W3, y0,y1,y2,y3);
      v[0][k]=y0; v[1][k]=y1; v[2][k]=y2; v[3][k]=y3;
    }
  }
  #pragma unroll
  for (int a = 0; a < 4; ++a)
    #pragma unroll
    for (int k = 0; k < 4; ++k)
      L[LSW(u + 64 * a + 256 * k)] = v[a][k];

  int D = u >> 2;
  float2 w[4][4];
  #pragma unroll
  for (int c = 0; c < 4; ++c)
    #pragma unroll
    for (int ap = 0; ap < 4; ++ap)
      w[c][ap] = L[LSW(64 * D + 16 * c + 4 * ap + tp)];
  #pragma unroll
  for (int ap = 0; ap < 4; ++ap) {
    float2 W1 = cmul(Ctw(64 * ap), tw16t);
    float2 W2 = cmul(W1, W1), W3 = cmul(W1, W2);
    float2 y0,y1,y2,y3;
    BFLY_F(w[0][ap], w[1][ap], w[2][ap], w[3][ap], W1, W2, W3, y0,y1,y2,y3);
    w[0][ap]=y0; w[1][ap]=y1; w[2][ap]=y2; w[3][ap]=y3;
  }
  {
    float2 W1 = tw64t, W2 = cmul(W1, W1), W3 = cmul(W1, W2);
    #pragma unroll
    for (int c = 0; c < 4; ++c) {
      float2 y0,y1,y2,y3;
      BFLY_F(w[c][0], w[c][1], w[c][2], w[c][3], W1, W2, W3, y0,y1,y2,y3);
      w[c][0]=y0; w[c][1]=y1; w[c][2]=y2; w[c][3]=y3;
    }
  }
  #pragma unroll
  for (int c = 0; c < 4; ++c)
    #pragma unroll
    for (int ap = 0; ap < 4; ++ap)
      L[LSW(64 * D + 16 * c + 4 * ap + tp)] = w[c][ap];

  float2* drow = dst + (size_t)row * 1024;
  #pragma unroll
  for (int j = 0; j < 4; ++j) {
    float2 z0 = L[LSW(16 * u + 4 * j)];
    float2 z1 = L[LSW(16 * u + 4 * j + 1)];
    float2 z2 = L[LSW(16 * u + 4 * j + 2)];
    float2 z3 = L[LSW(16 * u + 4 * j + 3)];
    float2 t0 = cadd(z0,z2), t1 = cadd(z1,z3), t2 = csub(z0,z2), d = csub(z1,z3);
    float2 t3 = make_float2(d.y, -d.x);
    float2 y0 = cadd(t0,t1), y1 = cadd(t2,t3), y2 = csub(t0,t1), y3 = csub(t2,t3);
    float4* dp = (float4*)(drow + 16 * u + 4 * j);
    dp[0] = make_float4(y0.x, y0.y, y1.x, y1.y);
    dp[1] = make_float4(y2.x, y2.y, y3.x, y3.y);
  }
  if (dorow) {
    #pragma unroll
    for (int m = 32; m; m >>= 1) rs += __shfl_down(rs, m);
    if (u == 0) out[row] = vbias[0] * rs;
  }
}

// ---- k_corr: all-named-scalar IFFT + logcosh, no per-thread arrays ----

#define PW(M, XA, XB, ZA, ZB) do { \
  float4 qa = W0p[M], qb = W1p[M]; \
  float2 g1 = cmulj(make_float2(qa.x,qa.y), XA); \
  float2 g2 = cmulj(make_float2(qb.x,qb.y), XA); \
  ZA = make_float2((g1.x-g2.y)*SCL, (g1.y+g2.x)*SCL); \
  g1 = cmulj(make_float2(qa.z,qa.w), XB); \
  g2 = cmulj(make_float2(qb.z,qb.w), XB); \
  ZB = make_float2((g1.x-g2.y)*SCL, (g1.y+g2.x)*SCL); } while(0)

#define PCPHASE(I) do { \
  float2 c0 = L[LSW(s4+(I))], c1 = L[LSW(s4+(I)+256)]; \
  float2 c2 = L[LSW(s4+(I)+512)], c3 = L[LSW(s4+(I)+768)]; \
  float2 W1 = cmul(tw4u, Ctw(I)); \
  float2 W2 = cmul(W1,W1), W3 = cmul(W1,W2); \
  BFLY_I(c0,c1,c2,c3,W1,W2,W3,c0,c1,c2,c3); \
  acc += lc(c0.x+bs0)+lc(c0.y+bs1)+lc(c1.x+bs0)+lc(c1.y+bs1); \
  acc += lc(c2.x+bs0)+lc(c2.y+bs1)+lc(c3.x+bs0)+lc(c3.y+bs1); } while(0)

#define QQPASS(QQ) do { \
  int p = wv * 2 + (QQ); \
  const float4* W0p = (const float4*)(Wfs + (size_t)(2*p) * 1024 + s16); \
  const float4* W1p = (const float4*)(Wfs + (size_t)(2*p+1) * 1024 + s16); \
  float bs0 = bs[2*p], bs1 = bs[2*p+1]; \
  float2 z0,z1,z2,z3,z4,z5,z6,z7,z8,z9,z10,z11,z12,z13,z14,z15; \
  PW(0, xr0, xr1, z0, z1);   PW(1, xr2, xr3, z2, z3); \
  PW(2, xr4, xr5, z4, z5);   PW(3, xr6, xr7, z6, z7); \
  PW(4, xr8, xr9, z8, z9);   PW(5, xr10, xr11, z10, z11); \
  PW(6, xr12, xr13, z12, z13); PW(7, xr14, xr15, z14, z15); \
  /* s0 */ \
  BFLY_I1(z0,z1,z2,z3, z0,z1,z2,z3); \
  BFLY_I1(z4,z5,z6,z7, z4,z5,z6,z7); \
  BFLY_I1(z8,z9,z10,z11, z8,z9,z10,z11); \
  BFLY_I1(z12,z13,z14,z15, z12,z13,z14,z15); \
  /* s1 */ \
  BFLY_I1(z0,z4,z8,z12, z0,z4,z8,z12); \
  BFLY_I(z1,z5,z9,z13, Ctw(64),Ctw(128),Ctw(192), z1,z5,z9,z13); \
  BFLY_I(z2,z6,z10,z14, Ctw(128),Ctw(256),Ctw(384), z2,z6,z10,z14); \
  BFLY_I(z3,z7,z11,z15, Ctw(192),Ctw(384),Ctw(576), z3,z7,z11,z15); \
  L[LSW(s16+0)]=z0;   L[LSW(s16+1)]=z1;   L[LSW(s16+2)]=z2;   L[LSW(s16+3)]=z3; \
  L[LSW(s16+4)]=z4;   L[LSW(s16+5)]=z5;   L[LSW(s16+6)]=z6;   L[LSW(s16+7)]=z7; \
  L[LSW(s16+8)]=z8;   L[LSW(s16+9)]=z9;   L[LSW(s16+10)]=z10; L[LSW(s16+11)]=z11; \
  L[LSW(s16+12)]=z12; L[LSW(s16+13)]=z13; L[LSW(s16+14)]=z14; L[LSW(s16+15)]=z15; \
  __builtin_amdgcn_sched_barrier(0); \
  /* s2+s3 on slots 256B + 64c + 16a + t (in-wave exchange; same-wave LDS is in-order) */ \
  float2 w00,w01,w02,w03,w10,w11,w12,w13,w20,w21,w22,w23,w30,w31,w32,w33; \
  w00 = L[LSW(sB+0)];   w01 = L[LSW(sB+64)];  w02 = L[LSW(sB+128)]; w03 = L[LSW(sB+192)]; \
  w10 = L[LSW(sB+16)];  w11 = L[LSW(sB+80)];  w12 = L[LSW(sB+144)]; w13 = L[LSW(sB+208)]; \
  w20 = L[LSW(sB+32)];  w21 = L[LSW(sB+96)];  w22 = L[LSW(sB+160)]; w23 = L[LSW(sB+224)]; \
  w30 = L[LSW(sB+48)];  w31 = L[LSW(sB+112)]; w32 = L[LSW(sB+176)]; w33 = L[LSW(sB+240)]; \
  { float2 W1 = tw16t, W2 = cmul(W1,W1), W3 = cmul(W1,W2); \
    BFLY_I(w00,w10,w20,w30, W1,W2,W3, w00,w10,w20,w30); \
    BFLY_I(w01,w11,w21,w31, W1,W2,W3, w01,w11,w21,w31); \
    BFLY_I(w02,w12,w22,w32, W1,W2,W3, w02,w12,w22,w32); \
    BFLY_I(w03,w13,w23,w33, W1,W2,W3, w03,w13,w23,w33); } \
  { float2 W1 = tw4t, W2 = cmul(W1,W1), W3 = cmul(W1,W2); \
    BFLY_I(w00,w01,w02,w03, W1,W2,W3, w00,w01,w02,w03); } \
  { float2 W1 = cmul(tw4t, Ctw(64)), W2 = cmul(W1,W1), W3 = cmul(W1,W2); \
    BFLY_I(w10,w11,w12,w13, W1,W2,W3, w10,w11,w12,w13); } \
  { float2 W1 = cmul(tw4t, Ctw(128)), W2 = cmul(W1,W1), W3 = cmul(W1,W2); \
    BFLY_I(w20,w21,w22,w23, W1,W2,W3, w20,w21,w22,w23); } \
  { float2 W1 = cmul(tw4t, Ctw(192)), W2 = cmul(W1,W1), W3 = cmul(W1,W2); \
    BFLY_I(w30,w31,w32,w33, W1,W2,W3, w30,w31,w32,w33); } \
  L[LSW(sB+0)]=w00;   L[LSW(sB+64)]=w01;  L[LSW(sB+128)]=w02; L[LSW(sB+192)]=w03; \
  L[LSW(sB+16)]=w10;  L[LSW(sB+80)]=w11;  L[LSW(sB+144)]=w12; L[LSW(sB+208)]=w13; \
  L[LSW(sB+32)]=w20;  L[LSW(sB+96)]=w21;  L[LSW(sB+160)]=w22; L[LSW(sB+224)]=w23; \
  L[LSW(sB+48)]=w30;  L[LSW(sB+112)]=w31; L[LSW(sB+176)]=w32; L[LSW(sB+240)]=w33; \
  __builtin_amdgcn_sched_barrier(0); \
  /* s4 + logcosh */ \
  PCPHASE(0); PCPHASE(1); PCPHASE(2); PCPHASE(3); \
  __builtin_amdgcn_sched_barrier(0); \
} while(0)

__global__ __launch_bounds__(256, 2) void k_corr(
    const float2* __restrict__ X, const float2* __restrict__ Wfs,
    const float* __restrict__ bs, const float2* __restrict__ tw,
    float* __restrict__ out) {
  __shared__ __align__(16) float2 fft[4][1024];
  __shared__ float red[4];
  int tid = threadIdx.x, wv = tid >> 6, u = tid & 63;
  int b = blockIdx.x;
  float2* L = fft[wv];
  float2 tw4u = tw[4 * u];
  int t = u & 15, B = u >> 4;
  float2 tw16t = tw[16 * t], tw4t = tw[4 * t];
  int s16 = 16 * u;
  int sB = 256 * B + t;
  int s4 = 4 * u;

  float2 xr0,xr1,xr2,xr3,xr4,xr5,xr6,xr7,xr8,xr9,xr10,xr11,xr12,xr13,xr14,xr15;
  {
    const float4* Xp = (const float4*)(X + (size_t)b * 1024 + s16);
    float4 q;
    q = Xp[0]; xr0  = make_float2(q.x,q.y); xr1  = make_float2(q.z,q.w);
    q = Xp[1]; xr2  = make_float2(q.x,q.y); xr3  = make_float2(q.z,q.w);
    q = Xp[2]; xr4  = make_float2(q.x,q.y); xr5  = make_float2(q.z,q.w);
    q = Xp[3]; xr6  = make_float2(q.x,q.y); xr7  = make_float2(q.z,q.w);
    q = Xp[4]; xr8  = make_float2(q.x,q.y); xr9  = make_float2(q.z,q.w);
    q = Xp[5]; xr10 = make_float2(q.x,q.y); xr11 = make_float2(q.z,q.w);
    q = Xp[6]; xr12 = make_float2(q.x,q.y); xr13 = make_float2(q.z,q.w);
    q = Xp[7]; xr14 = make_float2(q.x,q.y); xr15 = make_float2(q.z,q.w);
  }
  float acc = 0.f;
  QQPASS(0);
  QQPASS(1);

  #pragma unroll
  for (int m = 32; m; m >>= 1) acc += __shfl_down(acc, m);
  if (u == 0) red[wv] = acc;
  __syncthreads();
  if (tid == 0)
    out[b] += red[0] + red[1] + red[2] + red[3] - 16384.f * LN2F;
}

// fallback if workspace is too small: correct but slow
__global__ void k_naive(const float* __restrict__ x, const float* __restrict__ W,
                        const float* __restrict__ bs, const float* __restrict__ vb,
                        float* __restrict__ out) {
  int b = blockIdx.x;
  __shared__ float xs[1024];
  __shared__ float red[256];
  int t = threadIdx.x;
  float xsum = 0.f;
  for (int i = t; i < 1024; i += 256) { float v = x[(size_t)b * 1024 + i]; xs[i] = v; xsum += v; }
  __syncthreads();
  float tot = vb[0] * xsum;
  for (int h = t; h < 16384; h += 256) {
    int j = h >> 10, kh = h & 1023;
    float a = bs[j];
    for (int i = 0; i < 1024; ++i) a += xs[i] * W[((i + kh) & 1023) * 16 + j];
    float ax = fabsf(a);
    tot += ax + __logf(1.f + __expf(-2.f * ax)) - LN2F;
  }
  red[t] = tot;
  __syncthreads();
  for (int s2 = 128; s2; s2 >>= 1) { if (t < s2) red[t] += red[t + s2]; __syncthreads(); }
  if (t == 0) out[b] = red[0];
}

extern "C" void kernel_launch(void* const* d_in, const int* in_sizes, int n_in,
                              void* d_out, int out_size, void* d_ws, size_t ws_size,
                              hipStream_t stream) {
  const float* x  = (const float*)d_in[0];   // [4096,1024]
  const float* W  = (const float*)d_in[1];   // [1024,16]
  const float* bs = (const float*)d_in[2];   // [16]
  const float* vb = (const float*)d_in[3];   // [1]
  float* out = (float*)d_out;                // [4096]

  size_t need = 8192 + 131072 + (size_t)4096 * 1024 * 8;  // tw + Wfs + X
  if (ws_size < need) {
    k_naive<<<4096, 256, 0, stream>>>(x, W, bs, vb, out);
    return;
  }
  float2* tw  = (float2*)d_ws;
  float2* Wfs = (float2*)((char*)d_ws + 8192);
  float2* X   = (float2*)((char*)d_ws + 8192 + 131072);

  k_twiddle<<<4, 256, 0, stream>>>(tw);
  // 16 W-column spectra: w_j[m] = W[m*16 + j]
  k_fft_fwd<<<4, 256, 0, stream>>>(W, 16, 1, tw, Wfs, vb, out, 0);
  // 4096 x-row spectra; also out[row] = vb * rowsum(x[row])
  k_fft_fwd<<<1024, 256, 0, stream>>>(x, 1, 1024, tw, X, vb, out, 1);
  k_corr<<<4096, 256, 0, stream>>>(X, Wfs, bs, tw, out);
}

// Round 9
// 151.033 us; speedup vs baseline: 1.6813x; 1.0357x over previous
//
#include <hip/hip_runtime.h>
#include <hip/hip_bf16.h>
#include <math.h>

#define LN2F 0.6931471805599453f
#define SCL 9.765625e-4f   // 1/1024

typedef __attribute__((ext_vector_type(2))) float f32x2;

// ---------------------------------------------------------------------------
// Circulant trick: y[b, j*1024+i] = sum_k x[b,k] W[(i+k)%1024, j] is circular
// cross-correlation -> y_row = IDFT( Wf_j * conj(X_b) ), length-1024.
// Order irrelevant under sum(logcosh): radix-4 DIF forward (natural ->
// digit-reversed) + adjoint radix-4 DIT inverse, no bit reversal; pointwise
// product valid in permuted domain. 2 real outputs per complex IFFT.
// ALL complex arithmetic uses native 2-wide float vectors so the backend
// emits packed v_pk_{add,mul,fma}_f32 (CDNA4 dual-issue f32) instead of
// scalar ops -- k_corr was VALU-issue-bound at 61% with scalarized math.
// Zero per-thread arrays in k_corr (named scalars; round-7 spill lesson).
// ---------------------------------------------------------------------------

#define LSW(s) ((s) ^ (((s) >> 4) & 15))

__device__ __forceinline__ f32x2 mk2(float x, float y) { f32x2 r; r.x = x; r.y = y; return r; }
__device__ __forceinline__ f32x2 crot(f32x2 d) { return mk2(-d.y, d.x); }       // i*d
__device__ __forceinline__ f32x2 cmul(f32x2 a, f32x2 b) {                       // a*b
  return a.xx * b + mk2(-a.y, a.y) * b.yx;
}
__device__ __forceinline__ f32x2 cmulj(f32x2 a, f32x2 b) {                      // a*conj(b)
  return b.xx * a + mk2(b.y, -b.y) * a.yx;
}

// TWF[m] = e^{-2*pi*i*m/1024} for the compile-time m we need
__device__ __forceinline__ f32x2 Ctw(int m) {
  switch (m) {
    case 0:   return mk2(1.f, 0.f);
    case 1:   return mk2(0.999981175f, -0.006135885f);
    case 2:   return mk2(0.999924702f, -0.012271538f);
    case 3:   return mk2(0.999830582f, -0.018406730f);
    case 64:  return mk2(0.923879533f, -0.382683432f);
    case 128: return mk2(0.707106781f, -0.707106781f);
    case 192: return mk2(0.382683432f, -0.923879533f);
    case 256: return mk2(0.f, -1.f);
    case 384: return mk2(-0.707106781f, -0.707106781f);
    case 576: return mk2(-0.923879533f, 0.382683432f);
  }
  return mk2(1.f, 0.f);
}

// forward DIF butterfly (output twiddles, e^{-})
#define BFLY_F(x0,x1,x2,x3,W1,W2,W3,y0,y1,y2,y3) do { \
  f32x2 t0 = x0+x2, t1 = x1+x3, t2 = x0-x2, d_ = x1-x3; \
  f32x2 t3 = mk2(d_.y, -d_.x); \
  y0 = t0+t1; y1 = cmul(t2+t3, W1); \
  y2 = cmul(t0-t1, W2); y3 = cmul(t2-t3, W3); } while(0)

// inverse DIT butterfly (input conj-twiddles, e^{+})
#define BFLY_I(x0,x1,x2,x3,W1,W2,W3,y0,y1,y2,y3) do { \
  f32x2 u1 = cmulj(x1,W1), u2 = cmulj(x2,W2), u3 = cmulj(x3,W3); \
  f32x2 t0 = x0+u2, t1 = u1+u3, t2 = x0-u2, d_ = u1-u3; \
  f32x2 t3 = mk2(-d_.y, d_.x); \
  y0 = t0+t1; y1 = t2+t3; y2 = t0-t1; y3 = t2-t3; } while(0)

#define BFLY_I1(x0,x1,x2,x3,y0,y1,y2,y3) do { \
  f32x2 t0 = x0+x2, t1 = x1+x3, t2 = x0-x2, d_ = x1-x3; \
  f32x2 t3 = mk2(-d_.y, d_.x); \
  y0 = t0+t1; y1 = t2+t3; y2 = t0-t1; y3 = t2-t3; } while(0)

__device__ __forceinline__ float lc(float v) {  // logcosh + ln2
  float a = fabsf(v);
  return a + __logf(1.f + __expf(-2.f * a));
}

__global__ void k_twiddle(f32x2* __restrict__ tw) {
  int m = blockIdx.x * 256 + threadIdx.x;
  float th = (float)(2.0 * M_PI / 1024.0) * (float)m;
  tw[m] = mk2(cosf(th), -sinf(th));
}

// Forward FFT-1024 (radix-4 DIF). One wave per row, 4 rows/block. Real input.
__global__ __launch_bounds__(256, 3) void k_fft_fwd(
    const float* __restrict__ src, int estride, int rstride,
    const f32x2* __restrict__ tw, f32x2* __restrict__ dst,
    const float* __restrict__ vbias, float* __restrict__ out, int dorow) {
  __shared__ __align__(16) f32x2 fft[4][1024];
  int tid = threadIdx.x, wv = tid >> 6, u = tid & 63;
  int row = blockIdx.x * 4 + wv;
  const float* xr = src + (size_t)row * rstride;
  f32x2* L = fft[wv];
  f32x2 twu = tw[u];
  f32x2 tw4u = tw[4 * u];
  int tp = u & 3;
  f32x2 tw16t = tw[16 * tp], tw64t = tw[64 * tp];

  float vr[4][4]; float rs = 0.f;
  #pragma unroll
  for (int a = 0; a < 4; ++a)
    #pragma unroll
    for (int k = 0; k < 4; ++k) {
      float s = xr[(u + 64 * a + 256 * k) * estride];
      vr[a][k] = s; rs += s;
    }
  f32x2 v[4][4];
  #pragma unroll
  for (int a = 0; a < 4; ++a) {
    float x0 = vr[a][0], x1 = vr[a][1], x2 = vr[a][2], x3 = vr[a][3];
    float t0 = x0 + x2, t1 = x1 + x3, t2 = x0 - x2, dm = x1 - x3;
    f32x2 W1 = cmul(twu, Ctw(64 * a));
    f32x2 W2 = cmul(W1, W1), W3 = cmul(W1, W2);
    v[a][0] = mk2(t0 + t1, 0.f);
    v[a][1] = cmul(mk2(t2, -dm), W1);
    v[a][2] = cmul(mk2(t0 - t1, 0.f), W2);
    v[a][3] = cmul(mk2(t2, dm), W3);
  }
  {
    f32x2 W1 = tw4u, W2 = cmul(W1, W1), W3 = cmul(W1, W2);
    #pragma unroll
    for (int k = 0; k < 4; ++k) {
      f32x2 y0,y1,y2,y3;
      BFLY_F(v[0][k], v[1][k], v[2][k], v[3][k], W1, W2, W3, y0,y1,y2,y3);
      v[0][k]=y0; v[1][k]=y1; v[2][k]=y2; v[3][k]=y3;
    }
  }
  #pragma unroll
  for (int a = 0; a < 4; ++a)
    #pragma unroll
    for (int k = 0; k < 4; ++k)
      L[LSW(u + 64 * a + 256 * k)] = v[a][k];

  int D = u >> 2;
  f32x2 w[4][4];
  #pragma unroll
  for (int c = 0; c < 4; ++c)
    #pragma unroll
    for (int ap = 0; ap < 4; ++ap)
      w[c][ap] = L[LSW(64 * D + 16 * c + 4 * ap + tp)];
  #pragma unroll
  for (int ap = 0; ap < 4; ++ap) {
    f32x2 W1 = cmul(Ctw(64 * ap), tw16t);
    f32x2 W2 = cmul(W1, W1), W3 = cmul(W1, W2);
    f32x2 y0,y1,y2,y3;
    BFLY_F(w[0][ap], w[1][ap], w[2][ap], w[3][ap], W1, W2, W3, y0,y1,y2,y3);
    w[0][ap]=y0; w[1][ap]=y1; w[2][ap]=y2; w[3][ap]=y3;
  }
  {
    f32x2 W1 = tw64t, W2 = cmul(W1, W1), W3 = cmul(W1, W2);
    #pragma unroll
    for (int c = 0; c < 4; ++c) {
      f32x2 y0,y1,y2,y3;
      BFLY_F(w[c][0], w[c][1], w[c][2], w[c][3], W1, W2, W3, y0,y1,y2,y3);
      w[c][0]=y0; w[c][1]=y1; w[c][2]=y2; w[c][3]=y3;
    }
  }
  #pragma unroll
  for (int c = 0; c < 4; ++c)
    #pragma unroll
    for (int ap = 0; ap < 4; ++ap)
      L[LSW(64 * D + 16 * c + 4 * ap + tp)] = w[c][ap];

  f32x2* drow = dst + (size_t)row * 1024;
  #pragma unroll
  for (int j = 0; j < 4; ++j) {
    f32x2 z0 = L[LSW(16 * u + 4 * j)];
    f32x2 z1 = L[LSW(16 * u + 4 * j + 1)];
    f32x2 z2 = L[LSW(16 * u + 4 * j + 2)];
    f32x2 z3 = L[LSW(16 * u + 4 * j + 3)];
    f32x2 t0 = z0+z2, t1 = z1+z3, t2 = z0-z2, d = z1-z3;
    f32x2 t3 = mk2(d.y, -d.x);
    f32x2 y0 = t0+t1, y1 = t2+t3, y2 = t0-t1, y3 = t2-t3;
    float4* dp = (float4*)(drow + 16 * u + 4 * j);
    dp[0] = make_float4(y0.x, y0.y, y1.x, y1.y);
    dp[1] = make_float4(y2.x, y2.y, y3.x, y3.y);
  }
  if (dorow) {
    #pragma unroll
    for (int m = 32; m; m >>= 1) rs += __shfl_down(rs, m);
    if (u == 0) out[row] = vbias[0] * rs;
  }
}

// ---- k_corr: all-named-scalar IFFT + logcosh, packed-f32 complex math ----

#define PW(M, XA, XB, ZA, ZB) do { \
  float4 qa = W0p[M], qb = W1p[M]; \
  f32x2 g1 = cmulj(mk2(qa.x,qa.y), XA); \
  f32x2 g2 = cmulj(mk2(qb.x,qb.y), XA); \
  ZA = (g1 + crot(g2)) * SCL; \
  g1 = cmulj(mk2(qa.z,qa.w), XB); \
  g2 = cmulj(mk2(qb.z,qb.w), XB); \
  ZB = (g1 + crot(g2)) * SCL; } while(0)

#define PCPHASE(I) do { \
  f32x2 c0 = L[LSW(s4+(I))], c1 = L[LSW(s4+(I)+256)]; \
  f32x2 c2 = L[LSW(s4+(I)+512)], c3 = L[LSW(s4+(I)+768)]; \
  f32x2 W1 = cmul(tw4u, Ctw(I)); \
  f32x2 W2 = cmul(W1,W1), W3 = cmul(W1,W2); \
  BFLY_I(c0,c1,c2,c3,W1,W2,W3,c0,c1,c2,c3); \
  acc += lc(c0.x+bs0)+lc(c0.y+bs1)+lc(c1.x+bs0)+lc(c1.y+bs1); \
  acc += lc(c2.x+bs0)+lc(c2.y+bs1)+lc(c3.x+bs0)+lc(c3.y+bs1); } while(0)

#define QQPASS(QQ) do { \
  int p = wv * 2 + (QQ); \
  const float4* W0p = (const float4*)(Wfs + (size_t)(2*p) * 1024 + s16); \
  const float4* W1p = (const float4*)(Wfs + (size_t)(2*p+1) * 1024 + s16); \
  float bs0 = bs[2*p], bs1 = bs[2*p+1]; \
  f32x2 z0,z1,z2,z3,z4,z5,z6,z7,z8,z9,z10,z11,z12,z13,z14,z15; \
  PW(0, xr0, xr1, z0, z1);   PW(1, xr2, xr3, z2, z3); \
  PW(2, xr4, xr5, z4, z5);   PW(3, xr6, xr7, z6, z7); \
  PW(4, xr8, xr9, z8, z9);   PW(5, xr10, xr11, z10, z11); \
  PW(6, xr12, xr13, z12, z13); PW(7, xr14, xr15, z14, z15); \
  /* s0 */ \
  BFLY_I1(z0,z1,z2,z3, z0,z1,z2,z3); \
  BFLY_I1(z4,z5,z6,z7, z4,z5,z6,z7); \
  BFLY_I1(z8,z9,z10,z11, z8,z9,z10,z11); \
  BFLY_I1(z12,z13,z14,z15, z12,z13,z14,z15); \
  /* s1 */ \
  BFLY_I1(z0,z4,z8,z12, z0,z4,z8,z12); \
  BFLY_I(z1,z5,z9,z13, Ctw(64),Ctw(128),Ctw(192), z1,z5,z9,z13); \
  BFLY_I(z2,z6,z10,z14, Ctw(128),Ctw(256),Ctw(384), z2,z6,z10,z14); \
  BFLY_I(z3,z7,z11,z15, Ctw(192),Ctw(384),Ctw(576), z3,z7,z11,z15); \
  L[LSW(s16+0)]=z0;   L[LSW(s16+1)]=z1;   L[LSW(s16+2)]=z2;   L[LSW(s16+3)]=z3; \
  L[LSW(s16+4)]=z4;   L[LSW(s16+5)]=z5;   L[LSW(s16+6)]=z6;   L[LSW(s16+7)]=z7; \
  L[LSW(s16+8)]=z8;   L[LSW(s16+9)]=z9;   L[LSW(s16+10)]=z10; L[LSW(s16+11)]=z11; \
  L[LSW(s16+12)]=z12; L[LSW(s16+13)]=z13; L[LSW(s16+14)]=z14; L[LSW(s16+15)]=z15; \
  __builtin_amdgcn_sched_barrier(0); \
  /* s2+s3 on slots 256B + 64c + 16a + t (in-wave exchange) */ \
  f32x2 w00,w01,w02,w03,w10,w11,w12,w13,w20,w21,w22,w23,w30,w31,w32,w33; \
  w00 = L[LSW(sB+0)];   w01 = L[LSW(sB+64)];  w02 = L[LSW(sB+128)]; w03 = L[LSW(sB+192)]; \
  w10 = L[LSW(sB+16)];  w11 = L[LSW(sB+80)];  w12 = L[LSW(sB+144)]; w13 = L[LSW(sB+208)]; \
  w20 = L[LSW(sB+32)];  w21 = L[LSW(sB+96)];  w22 = L[LSW(sB+160)]; w23 = L[LSW(sB+224)]; \
  w30 = L[LSW(sB+48)];  w31 = L[LSW(sB+112)]; w32 = L[LSW(sB+176)]; w33 = L[LSW(sB+240)]; \
  { f32x2 W1 = tw16t, W2 = cmul(W1,W1), W3 = cmul(W1,W2); \
    BFLY_I(w00,w10,w20,w30, W1,W2,W3, w00,w10,w20,w30); \
    BFLY_I(w01,w11,w21,w31, W1,W2,W3, w01,w11,w21,w31); \
    BFLY_I(w02,w12,w22,w32, W1,W2,W3, w02,w12,w22,w32); \
    BFLY_I(w03,w13,w23,w33, W1,W2,W3, w03,w13,w23,w33); } \
  { f32x2 W1 = tw4t, W2 = cmul(W1,W1), W3 = cmul(W1,W2); \
    BFLY_I(w00,w01,w02,w03, W1,W2,W3, w00,w01,w02,w03); } \
  { f32x2 W1 = cmul(tw4t, Ctw(64)), W2 = cmul(W1,W1), W3 = cmul(W1,W2); \
    BFLY_I(w10,w11,w12,w13, W1,W2,W3, w10,w11,w12,w13); } \
  { f32x2 W1 = cmul(tw4t, Ctw(128)), W2 = cmul(W1,W1), W3 = cmul(W1,W2); \
    BFLY_I(w20,w21,w22,w23, W1,W2,W3, w20,w21,w22,w23); } \
  { f32x2 W1 = cmul(tw4t, Ctw(192)), W2 = cmul(W1,W1), W3 = cmul(W1,W2); \
    BFLY_I(w30,w31,w32,w33, W1,W2,W3, w30,w31,w32,w33); } \
  L[LSW(sB+0)]=w00;   L[LSW(sB+64)]=w01;  L[LSW(sB+128)]=w02; L[LSW(sB+192)]=w03; \
  L[LSW(sB+16)]=w10;  L[LSW(sB+80)]=w11;  L[LSW(sB+144)]=w12; L[LSW(sB+208)]=w13; \
  L[LSW(sB+32)]=w20;  L[LSW(sB+96)]=w21;  L[LSW(sB+160)]=w22; L[LSW(sB+224)]=w23; \
  L[LSW(sB+48)]=w30;  L[LSW(sB+112)]=w31; L[LSW(sB+176)]=w32; L[LSW(sB+240)]=w33; \
  __builtin_amdgcn_sched_barrier(0); \
  /* s4 + logcosh */ \
  PCPHASE(0); PCPHASE(1); PCPHASE(2); PCPHASE(3); \
  __builtin_amdgcn_sched_barrier(0); \
} while(0)

__global__ __launch_bounds__(256, 2) void k_corr(
    const f32x2* __restrict__ X, const f32x2* __restrict__ Wfs,
    const float* __restrict__ bs, const f32x2* __restrict__ tw,
    float* __restrict__ out) {
  __shared__ __align__(16) f32x2 fft[4][1024];
  __shared__ float red[4];
  int tid = threadIdx.x, wv = tid >> 6, u = tid & 63;
  int b = blockIdx.x;
  f32x2* L = fft[wv];
  f32x2 tw4u = tw[4 * u];
  int t = u & 15, B = u >> 4;
  f32x2 tw16t = tw[16 * t], tw4t = tw[4 * t];
  int s16 = 16 * u;
  int sB = 256 * B + t;
  int s4 = 4 * u;

  f32x2 xr0,xr1,xr2,xr3,xr4,xr5,xr6,xr7,xr8,xr9,xr10,xr11,xr12,xr13,xr14,xr15;
  {
    const float4* Xp = (const float4*)(X + (size_t)b * 1024 + s16);
    float4 q;
    q = Xp[0]; xr0  = mk2(q.x,q.y); xr1  = mk2(q.z,q.w);
    q = Xp[1]; xr2  = mk2(q.x,q.y); xr3  = mk2(q.z,q.w);
    q = Xp[2]; xr4  = mk2(q.x,q.y); xr5  = mk2(q.z,q.w);
    q = Xp[3]; xr6  = mk2(q.x,q.y); xr7  = mk2(q.z,q.w);
    q = Xp[4]; xr8  = mk2(q.x,q.y); xr9  = mk2(q.z,q.w);
    q = Xp[5]; xr10 = mk2(q.x,q.y); xr11 = mk2(q.z,q.w);
    q = Xp[6]; xr12 = mk2(q.x,q.y); xr13 = mk2(q.z,q.w);
    q = Xp[7]; xr14 = mk2(q.x,q.y); xr15 = mk2(q.z,q.w);
  }
  float acc = 0.f;
  QQPASS(0);
  QQPASS(1);

  #pragma unroll
  for (int m = 32; m; m >>= 1) acc += __shfl_down(acc, m);
  if (u == 0) red[wv] = acc;
  __syncthreads();
  if (tid == 0)
    out[b] += red[0] + red[1] + red[2] + red[3] - 16384.f * LN2F;
}

// fallback if workspace is too small: correct but slow
__global__ void k_naive(const float* __restrict__ x, const float* __restrict__ W,
                        const float* __restrict__ bs, const float* __restrict__ vb,
                        float* __restrict__ out) {
  int b = blockIdx.x;
  __shared__ float xs[1024];
  __shared__ float red[256];
  int t = threadIdx.x;
  float xsum = 0.f;
  for (int i = t; i < 1024; i += 256) { float v = x[(size_t)b * 1024 + i]; xs[i] = v; xsum += v; }
  __syncthreads();
  float tot = vb[0] * xsum;
  for (int h = t; h < 16384; h += 256) {
    int j = h >> 10, kh = h & 1023;
    float a = bs[j];
    for (int i = 0; i < 1024; ++i) a += xs[i] * W[((i + kh) & 1023) * 16 + j];
    float ax = fabsf(a);
    tot += ax + __logf(1.f + __expf(-2.f * ax)) - LN2F;
  }
  red[t] = tot;
  __syncthreads();
  for (int s2 = 128; s2; s2 >>= 1) { if (t < s2) red[t] += red[t + s2]; __syncthreads(); }
  if (t == 0) out[b] = red[0];
}

extern "C" void kernel_launch(void* const* d_in, const int* in_sizes, int n_in,
                              void* d_out, int out_size, void* d_ws, size_t ws_size,
                              hipStream_t stream) {
  const float* x  = (const float*)d_in[0];   // [4096,1024]
  const float* W  = (const float*)d_in[1];   // [1024,16]
  const float* bs = (const float*)d_in[2];   // [16]
  const float* vb = (const float*)d_in[3];   // [1]
  float* out = (float*)d_out;                // [4096]

  size_t need = 8192 + 131072 + (size_t)4096 * 1024 * 8;  // tw + Wfs + X
  if (ws_size < need) {
    k_naive<<<4096, 256, 0, stream>>>(x, W, bs, vb, out);
    return;
  }
  f32x2* tw  = (f32x2*)d_ws;
  f32x2* Wfs = (f32x2*)((char*)d_ws + 8192);
  f32x2* X   = (f32x2*)((char*)d_ws + 8192 + 131072);

  k_twiddle<<<4, 256, 0, stream>>>(tw);
  // 16 W-column spectra: w_j[m] = W[m*16 + j]
  k_fft_fwd<<<4, 256, 0, stream>>>(W, 16, 1, tw, Wfs, vb, out, 0);
  // 4096 x-row spectra; also out[row] = vb * rowsum(x[row])
  k_fft_fwd<<<1024, 256, 0, stream>>>(x, 1, 1024, tw, X, vb, out, 1);
  k_corr<<<4096, 256, 0, stream>>>(X, Wfs, bs, tw, out);
}

// Round 10
// 135.556 us; speedup vs baseline: 1.8732x; 1.1142x over previous
//
#include <hip/hip_runtime.h>
#include <hip/hip_bf16.h>
#include <math.h>

#define LN2F 0.6931471805599453f
#define SCL 9.765625e-4f   // 1/1024

typedef __attribute__((ext_vector_type(2))) float f32x2;

// ---------------------------------------------------------------------------
// Circulant trick: y[b, j*1024+i] = sum_k x[b,k] W[(i+k)%1024, j] is circular
// cross-correlation -> y_row = IDFT( Wf_j * conj(X_b) ), length-1024.
// Order irrelevant under sum(logcosh): radix-4 DIF forward + adjoint radix-4
// DIT inverse, no bit reversal. 2 real outputs per complex IFFT.
// k_corr: the two j-pair passes are software-pipelined at phase granularity
// (A=pointwise+s0+s1+LDSwrite, B=read+s2s3+write, C=read+s4+logcosh), with
// DISJOINT per-pass LDS buffers so phases of different passes have no memory
// deps -> each phase's VALU covers the other's LDS latency (round 9 was 48%
// stall at 2 waves/SIMD). Shared twiddle chains hoisted; 4-way acc split.
// Zero per-thread arrays (round-7 spill lesson); no sched_barriers.
// ---------------------------------------------------------------------------

#define LSW(s) ((s) ^ (((s) >> 4) & 15))

__device__ __forceinline__ f32x2 mk2(float x, float y) { f32x2 r; r.x = x; r.y = y; return r; }
__device__ __forceinline__ f32x2 crot(f32x2 d) { return mk2(-d.y, d.x); }       // i*d
__device__ __forceinline__ f32x2 cmul(f32x2 a, f32x2 b) {                       // a*b
  return a.xx * b + mk2(-a.y, a.y) * b.yx;
}
__device__ __forceinline__ f32x2 cmulj(f32x2 a, f32x2 b) {                      // a*conj(b)
  return b.xx * a + mk2(b.y, -b.y) * a.yx;
}

// TWF[m] = e^{-2*pi*i*m/1024} for the compile-time m we need
__device__ __forceinline__ f32x2 Ctw(int m) {
  switch (m) {
    case 0:   return mk2(1.f, 0.f);
    case 1:   return mk2(0.999981175f, -0.006135885f);
    case 2:   return mk2(0.999924702f, -0.012271538f);
    case 3:   return mk2(0.999830582f, -0.018406730f);
    case 64:  return mk2(0.923879533f, -0.382683432f);
    case 128: return mk2(0.707106781f, -0.707106781f);
    case 192: return mk2(0.382683432f, -0.923879533f);
    case 256: return mk2(0.f, -1.f);
    case 384: return mk2(-0.707106781f, -0.707106781f);
    case 576: return mk2(-0.923879533f, 0.382683432f);
  }
  return mk2(1.f, 0.f);
}

// forward DIF butterfly (output twiddles, e^{-})
#define BFLY_F(x0,x1,x2,x3,W1,W2,W3,y0,y1,y2,y3) do { \
  f32x2 t0 = x0+x2, t1 = x1+x3, t2 = x0-x2, d_ = x1-x3; \
  f32x2 t3 = mk2(d_.y, -d_.x); \
  y0 = t0+t1; y1 = cmul(t2+t3, W1); \
  y2 = cmul(t0-t1, W2); y3 = cmul(t2-t3, W3); } while(0)

// inverse DIT butterfly (input conj-twiddles, e^{+})
#define BFLY_I(x0,x1,x2,x3,W1,W2,W3,y0,y1,y2,y3) do { \
  f32x2 u1 = cmulj(x1,W1), u2 = cmulj(x2,W2), u3 = cmulj(x3,W3); \
  f32x2 t0 = x0+u2, t1 = u1+u3, t2 = x0-u2, d_ = u1-u3; \
  f32x2 t3 = mk2(-d_.y, d_.x); \
  y0 = t0+t1; y1 = t2+t3; y2 = t0-t1; y3 = t2-t3; } while(0)

#define BFLY_I1(x0,x1,x2,x3,y0,y1,y2,y3) do { \
  f32x2 t0 = x0+x2, t1 = x1+x3, t2 = x0-x2, d_ = x1-x3; \
  f32x2 t3 = mk2(-d_.y, d_.x); \
  y0 = t0+t1; y1 = t2+t3; y2 = t0-t1; y3 = t2-t3; } while(0)

__device__ __forceinline__ float lc(float v) {  // logcosh + ln2
  float a = fabsf(v);
  return a + __logf(1.f + __expf(-2.f * a));
}

__global__ void k_twiddle(f32x2* __restrict__ tw) {
  int m = blockIdx.x * 256 + threadIdx.x;
  float th = (float)(2.0 * M_PI / 1024.0) * (float)m;
  tw[m] = mk2(cosf(th), -sinf(th));
}

// Forward FFT-1024 (radix-4 DIF). One wave per row, 4 rows/block. Real input.
__global__ __launch_bounds__(256, 3) void k_fft_fwd(
    const float* __restrict__ src, int estride, int rstride,
    const f32x2* __restrict__ tw, f32x2* __restrict__ dst,
    const float* __restrict__ vbias, float* __restrict__ out, int dorow) {
  __shared__ __align__(16) f32x2 fft[4][1024];
  int tid = threadIdx.x, wv = tid >> 6, u = tid & 63;
  int row = blockIdx.x * 4 + wv;
  const float* xr = src + (size_t)row * rstride;
  f32x2* L = fft[wv];
  f32x2 twu = tw[u];
  f32x2 tw4u = tw[4 * u];
  int tp = u & 3;
  f32x2 tw16t = tw[16 * tp], tw64t = tw[64 * tp];

  float vr[4][4]; float rs = 0.f;
  #pragma unroll
  for (int a = 0; a < 4; ++a)
    #pragma unroll
    for (int k = 0; k < 4; ++k) {
      float s = xr[(u + 64 * a + 256 * k) * estride];
      vr[a][k] = s; rs += s;
    }
  f32x2 v[4][4];
  #pragma unroll
  for (int a = 0; a < 4; ++a) {
    float x0 = vr[a][0], x1 = vr[a][1], x2 = vr[a][2], x3 = vr[a][3];
    float t0 = x0 + x2, t1 = x1 + x3, t2 = x0 - x2, dm = x1 - x3;
    f32x2 W1 = cmul(twu, Ctw(64 * a));
    f32x2 W2 = cmul(W1, W1), W3 = cmul(W1, W2);
    v[a][0] = mk2(t0 + t1, 0.f);
    v[a][1] = cmul(mk2(t2, -dm), W1);
    v[a][2] = cmul(mk2(t0 - t1, 0.f), W2);
    v[a][3] = cmul(mk2(t2, dm), W3);
  }
  {
    f32x2 W1 = tw4u, W2 = cmul(W1, W1), W3 = cmul(W1, W2);
    #pragma unroll
    for (int k = 0; k < 4; ++k) {
      f32x2 y0,y1,y2,y3;
      BFLY_F(v[0][k], v[1][k], v[2][k], v[3][k], W1, W2, W3, y0,y1,y2,y3);
      v[0][k]=y0; v[1][k]=y1; v[2][k]=y2; v[3][k]=y3;
    }
  }
  #pragma unroll
  for (int a = 0; a < 4; ++a)
    #pragma unroll
    for (int k = 0; k < 4; ++k)
      L[LSW(u + 64 * a + 256 * k)] = v[a][k];

  int D = u >> 2;
  f32x2 w[4][4];
  #pragma unroll
  for (int c = 0; c < 4; ++c)
    #pragma unroll
    for (int ap = 0; ap < 4; ++ap)
      w[c][ap] = L[LSW(64 * D + 16 * c + 4 * ap + tp)];
  #pragma unroll
  for (int ap = 0; ap < 4; ++ap) {
    f32x2 W1 = cmul(Ctw(64 * ap), tw16t);
    f32x2 W2 = cmul(W1, W1), W3 = cmul(W1, W2);
    f32x2 y0,y1,y2,y3;
    BFLY_F(w[0][ap], w[1][ap], w[2][ap], w[3][ap], W1, W2, W3, y0,y1,y2,y3);
    w[0][ap]=y0; w[1][ap]=y1; w[2][ap]=y2; w[3][ap]=y3;
  }
  {
    f32x2 W1 = tw64t, W2 = cmul(W1, W1), W3 = cmul(W1, W2);
    #pragma unroll
    for (int c = 0; c < 4; ++c) {
      f32x2 y0,y1,y2,y3;
      BFLY_F(w[c][0], w[c][1], w[c][2], w[c][3], W1, W2, W3, y0,y1,y2,y3);
      w[c][0]=y0; w[c][1]=y1; w[c][2]=y2; w[c][3]=y3;
    }
  }
  #pragma unroll
  for (int c = 0; c < 4; ++c)
    #pragma unroll
    for (int ap = 0; ap < 4; ++ap)
      L[LSW(64 * D + 16 * c + 4 * ap + tp)] = w[c][ap];

  f32x2* drow = dst + (size_t)row * 1024;
  #pragma unroll
  for (int j = 0; j < 4; ++j) {
    f32x2 z0 = L[LSW(16 * u + 4 * j)];
    f32x2 z1 = L[LSW(16 * u + 4 * j + 1)];
    f32x2 z2 = L[LSW(16 * u + 4 * j + 2)];
    f32x2 z3 = L[LSW(16 * u + 4 * j + 3)];
    f32x2 t0 = z0+z2, t1 = z1+z3, t2 = z0-z2, d = z1-z3;
    f32x2 t3 = mk2(d.y, -d.x);
    f32x2 y0 = t0+t1, y1 = t2+t3, y2 = t0-t1, y3 = t2-t3;
    float4* dp = (float4*)(drow + 16 * u + 4 * j);
    dp[0] = make_float4(y0.x, y0.y, y1.x, y1.y);
    dp[1] = make_float4(y2.x, y2.y, y3.x, y3.y);
  }
  if (dorow) {
    #pragma unroll
    for (int m = 32; m; m >>= 1) rs += __shfl_down(rs, m);
    if (u == 0) out[row] = vbias[0] * rs;
  }
}

// ---- k_corr phase macros (named scalars; phases of the two passes are
// ---- issued A0 A1 B0 B1 C0 C1 against disjoint LDS buffers) ----

#define PW(M, XA, XB, ZA, ZB) do { \
  float4 qa = W0p[M], qb = W1p[M]; \
  f32x2 g1 = cmulj(mk2(qa.x,qa.y), XA); \
  f32x2 g2 = cmulj(mk2(qb.x,qb.y), XA); \
  ZA = (g1 + crot(g2)) * SCL; \
  g1 = cmulj(mk2(qa.z,qa.w), XB); \
  g2 = cmulj(mk2(qb.z,qb.w), XB); \
  ZB = (g1 + crot(g2)) * SCL; } while(0)

#define QP_A(QQ, LB) do { \
  const float4* W0p = (const float4*)(Wfs + (size_t)(4*wv + 2*(QQ)) * 1024 + s16); \
  const float4* W1p = (const float4*)(Wfs + (size_t)(4*wv + 2*(QQ) + 1) * 1024 + s16); \
  f32x2 z0,z1,z2,z3,z4,z5,z6,z7,z8,z9,z10,z11,z12,z13,z14,z15; \
  PW(0, xr0, xr1, z0, z1);   PW(1, xr2, xr3, z2, z3); \
  PW(2, xr4, xr5, z4, z5);   PW(3, xr6, xr7, z6, z7); \
  PW(4, xr8, xr9, z8, z9);   PW(5, xr10, xr11, z10, z11); \
  PW(6, xr12, xr13, z12, z13); PW(7, xr14, xr15, z14, z15); \
  /* s0 */ \
  BFLY_I1(z0,z1,z2,z3, z0,z1,z2,z3); \
  BFLY_I1(z4,z5,z6,z7, z4,z5,z6,z7); \
  BFLY_I1(z8,z9,z10,z11, z8,z9,z10,z11); \
  BFLY_I1(z12,z13,z14,z15, z12,z13,z14,z15); \
  /* s1 */ \
  BFLY_I1(z0,z4,z8,z12, z0,z4,z8,z12); \
  BFLY_I(z1,z5,z9,z13, Ctw(64),Ctw(128),Ctw(192), z1,z5,z9,z13); \
  BFLY_I(z2,z6,z10,z14, Ctw(128),Ctw(256),Ctw(384), z2,z6,z10,z14); \
  BFLY_I(z3,z7,z11,z15, Ctw(192),Ctw(384),Ctw(576), z3,z7,z11,z15); \
  (LB)[LSW(s16+0)]=z0;   (LB)[LSW(s16+1)]=z1;   (LB)[LSW(s16+2)]=z2;   (LB)[LSW(s16+3)]=z3; \
  (LB)[LSW(s16+4)]=z4;   (LB)[LSW(s16+5)]=z5;   (LB)[LSW(s16+6)]=z6;   (LB)[LSW(s16+7)]=z7; \
  (LB)[LSW(s16+8)]=z8;   (LB)[LSW(s16+9)]=z9;   (LB)[LSW(s16+10)]=z10; (LB)[LSW(s16+11)]=z11; \
  (LB)[LSW(s16+12)]=z12; (LB)[LSW(s16+13)]=z13; (LB)[LSW(s16+14)]=z14; (LB)[LSW(s16+15)]=z15; \
} while(0)

#define QP_B(LB) do { \
  f32x2 w00,w01,w02,w03,w10,w11,w12,w13,w20,w21,w22,w23,w30,w31,w32,w33; \
  w00 = (LB)[LSW(sB+0)];   w01 = (LB)[LSW(sB+64)];  w02 = (LB)[LSW(sB+128)]; w03 = (LB)[LSW(sB+192)]; \
  w10 = (LB)[LSW(sB+16)];  w11 = (LB)[LSW(sB+80)];  w12 = (LB)[LSW(sB+144)]; w13 = (LB)[LSW(sB+208)]; \
  w20 = (LB)[LSW(sB+32)];  w21 = (LB)[LSW(sB+96)];  w22 = (LB)[LSW(sB+160)]; w23 = (LB)[LSW(sB+224)]; \
  w30 = (LB)[LSW(sB+48)];  w31 = (LB)[LSW(sB+112)]; w32 = (LB)[LSW(sB+176)]; w33 = (LB)[LSW(sB+240)]; \
  BFLY_I(w00,w10,w20,w30, TB1,TB2,TB3, w00,w10,w20,w30); \
  BFLY_I(w01,w11,w21,w31, TB1,TB2,TB3, w01,w11,w21,w31); \
  BFLY_I(w02,w12,w22,w32, TB1,TB2,TB3, w02,w12,w22,w32); \
  BFLY_I(w03,w13,w23,w33, TB1,TB2,TB3, w03,w13,w23,w33); \
  BFLY_I(w00,w01,w02,w03, TC10,TC20,TC30, w00,w01,w02,w03); \
  BFLY_I(w10,w11,w12,w13, TC11,TC21,TC31, w10,w11,w12,w13); \
  BFLY_I(w20,w21,w22,w23, TC12,TC22,TC32, w20,w21,w22,w23); \
  BFLY_I(w30,w31,w32,w33, TC13,TC23,TC33, w30,w31,w32,w33); \
  (LB)[LSW(sB+0)]=w00;   (LB)[LSW(sB+64)]=w01;  (LB)[LSW(sB+128)]=w02; (LB)[LSW(sB+192)]=w03; \
  (LB)[LSW(sB+16)]=w10;  (LB)[LSW(sB+80)]=w11;  (LB)[LSW(sB+144)]=w12; (LB)[LSW(sB+208)]=w13; \
  (LB)[LSW(sB+32)]=w20;  (LB)[LSW(sB+96)]=w21;  (LB)[LSW(sB+160)]=w22; (LB)[LSW(sB+224)]=w23; \
  (LB)[LSW(sB+48)]=w30;  (LB)[LSW(sB+112)]=w31; (LB)[LSW(sB+176)]=w32; (LB)[LSW(sB+240)]=w33; \
} while(0)

#define QPC_PH(LB, I, T1, T2, T3, BS0, BS1) do { \
  f32x2 c0 = (LB)[LSW(s4+(I))],     c1 = (LB)[LSW(s4+(I)+256)]; \
  f32x2 c2 = (LB)[LSW(s4+(I)+512)], c3 = (LB)[LSW(s4+(I)+768)]; \
  BFLY_I(c0,c1,c2,c3,T1,T2,T3,c0,c1,c2,c3); \
  a0 += lc(c0.x+(BS0)) + lc(c0.y+(BS1)); \
  a1 += lc(c1.x+(BS0)) + lc(c1.y+(BS1)); \
  a2 += lc(c2.x+(BS0)) + lc(c2.y+(BS1)); \
  a3 += lc(c3.x+(BS0)) + lc(c3.y+(BS1)); } while(0)

#define QP_C(LB, BS0, BS1) do { \
  QPC_PH(LB, 0, TD10, TD20, TD30, BS0, BS1); \
  QPC_PH(LB, 1, TD11, TD21, TD31, BS0, BS1); \
  QPC_PH(LB, 2, TD12, TD22, TD32, BS0, BS1); \
  QPC_PH(LB, 3, TD13, TD23, TD33, BS0, BS1); } while(0)

__global__ __launch_bounds__(256, 2) void k_corr(
    const f32x2* __restrict__ X, const f32x2* __restrict__ Wfs,
    const float* __restrict__ bs, const f32x2* __restrict__ tw,
    float* __restrict__ out) {
  __shared__ __align__(16) f32x2 LBW[4][2][1024];   // [wave][pass][slot]
  __shared__ float red[4];
  int tid = threadIdx.x, wv = tid >> 6, u = tid & 63;
  int b = blockIdx.x;
  f32x2* L0 = LBW[wv][0];
  f32x2* L1 = LBW[wv][1];
  f32x2 tw4u = tw[4 * u];
  int t = u & 15;
  f32x2 tw16t = tw[16 * t], tw4t = tw[4 * t];
  int s16 = 16 * u;
  int sB = 256 * (u >> 4) + t;
  int s4 = 4 * u;

  f32x2 xr0,xr1,xr2,xr3,xr4,xr5,xr6,xr7,xr8,xr9,xr10,xr11,xr12,xr13,xr14,xr15;
  {
    const float4* Xp = (const float4*)(X + (size_t)b * 1024 + s16);
    float4 q;
    q = Xp[0]; xr0  = mk2(q.x,q.y); xr1  = mk2(q.z,q.w);
    q = Xp[1]; xr2  = mk2(q.x,q.y); xr3  = mk2(q.z,q.w);
    q = Xp[2]; xr4  = mk2(q.x,q.y); xr5  = mk2(q.z,q.w);
    q = Xp[3]; xr6  = mk2(q.x,q.y); xr7  = mk2(q.z,q.w);
    q = Xp[4]; xr8  = mk2(q.x,q.y); xr9  = mk2(q.z,q.w);
    q = Xp[5]; xr10 = mk2(q.x,q.y); xr11 = mk2(q.z,q.w);
    q = Xp[6]; xr12 = mk2(q.x,q.y); xr13 = mk2(q.z,q.w);
    q = Xp[7]; xr14 = mk2(q.x,q.y); xr15 = mk2(q.z,q.w);
  }
  float bsA0 = bs[4*wv], bsA1 = bs[4*wv+1], bsB0 = bs[4*wv+2], bsB1 = bs[4*wv+3];

  // phase A of both passes (pointwise + s0 + s1 + LDS write)
  QP_A(0, L0);
  QP_A(1, L1);

  // hoisted s2/s3 twiddles (shared by both passes)
  f32x2 TB1 = tw16t, TB2 = cmul(TB1,TB1), TB3 = cmul(TB1,TB2);
  f32x2 TC10 = tw4t,               TC20 = cmul(TC10,TC10), TC30 = cmul(TC10,TC20);
  f32x2 TC11 = cmul(tw4t,Ctw(64)),  TC21 = cmul(TC11,TC11), TC31 = cmul(TC11,TC21);
  f32x2 TC12 = cmul(tw4t,Ctw(128)), TC22 = cmul(TC12,TC12), TC32 = cmul(TC12,TC22);
  f32x2 TC13 = cmul(tw4t,Ctw(192)), TC23 = cmul(TC13,TC13), TC33 = cmul(TC13,TC23);

  // phase B of both passes (read + s2 + s3 + write)
  QP_B(L0);
  QP_B(L1);

  // hoisted s4 twiddles (shared by both passes)
  f32x2 TD10 = tw4u,              TD20 = cmul(TD10,TD10), TD30 = cmul(TD10,TD20);
  f32x2 TD11 = cmul(tw4u,Ctw(1)), TD21 = cmul(TD11,TD11), TD31 = cmul(TD11,TD21);
  f32x2 TD12 = cmul(tw4u,Ctw(2)), TD22 = cmul(TD12,TD12), TD32 = cmul(TD12,TD22);
  f32x2 TD13 = cmul(tw4u,Ctw(3)), TD23 = cmul(TD13,TD13), TD33 = cmul(TD13,TD23);

  // phase C of both passes (read + s4 + logcosh)
  float a0 = 0.f, a1 = 0.f, a2 = 0.f, a3 = 0.f;
  QP_C(L0, bsA0, bsA1);
  QP_C(L1, bsB0, bsB1);

  float acc = (a0 + a1) + (a2 + a3);
  #pragma unroll
  for (int m = 32; m; m >>= 1) acc += __shfl_down(acc, m);
  if (u == 0) red[wv] = acc;
  __syncthreads();
  if (tid == 0)
    out[b] += red[0] + red[1] + red[2] + red[3] - 16384.f * LN2F;
}

// fallback if workspace is too small: correct but slow
__global__ void k_naive(const float* __restrict__ x, const float* __restrict__ W,
                        const float* __restrict__ bs, const float* __restrict__ vb,
                        float* __restrict__ out) {
  int b = blockIdx.x;
  __shared__ float xs[1024];
  __shared__ float red[256];
  int t = threadIdx.x;
  float xsum = 0.f;
  for (int i = t; i < 1024; i += 256) { float v = x[(size_t)b * 1024 + i]; xs[i] = v; xsum += v; }
  __syncthreads();
  float tot = vb[0] * xsum;
  for (int h = t; h < 16384; h += 256) {
    int j = h >> 10, kh = h & 1023;
    float a = bs[j];
    for (int i = 0; i < 1024; ++i) a += xs[i] * W[((i + kh) & 1023) * 16 + j];
    float ax = fabsf(a);
    tot += ax + __logf(1.f + __expf(-2.f * ax)) - LN2F;
  }
  red[t] = tot;
  __syncthreads();
  for (int s2 = 128; s2; s2 >>= 1) { if (t < s2) red[t] += red[t + s2]; __syncthreads(); }
  if (t == 0) out[b] = red[0];
}

extern "C" void kernel_launch(void* const* d_in, const int* in_sizes, int n_in,
                              void* d_out, int out_size, void* d_ws, size_t ws_size,
                              hipStream_t stream) {
  const float* x  = (const float*)d_in[0];   // [4096,1024]
  const float* W  = (const float*)d_in[1];   // [1024,16]
  const float* bs = (const float*)d_in[2];   // [16]
  const float* vb = (const float*)d_in[3];   // [1]
  float* out = (float*)d_out;                // [4096]

  size_t need = 8192 + 131072 + (size_t)4096 * 1024 * 8;  // tw + Wfs + X
  if (ws_size < need) {
    k_naive<<<4096, 256, 0, stream>>>(x, W, bs, vb, out);
    return;
  }
  f32x2* tw  = (f32x2*)d_ws;
  f32x2* Wfs = (f32x2*)((char*)d_ws + 8192);
  f32x2* X   = (f32x2*)((char*)d_ws + 8192 + 131072);

  k_twiddle<<<4, 256, 0, stream>>>(tw);
  // 16 W-column spectra: w_j[m] = W[m*16 + j]
  k_fft_fwd<<<4, 256, 0, stream>>>(W, 16, 1, tw, Wfs, vb, out, 0);
  // 4096 x-row spectra; also out[row] = vb * rowsum(x[row])
  k_fft_fwd<<<1024, 256, 0, stream>>>(x, 1, 1024, tw, X, vb, out, 1);
  k_corr<<<4096, 256, 0, stream>>>(X, Wfs, bs, tw, out);
}